// Round 1
// baseline (232.506 us; speedup 1.0000x reference)
//
#include <hip/hip_runtime.h>
#include <hip/hip_bf16.h>

// ---------------- problem constants ----------------
namespace {
constexpr int kB = 1, kT = 2, kV = 3;
constexpr int kGH = 32, kGW = 64;
constexpr int kNG = kV * kGH * kGW;      // 6144 gaussians per (b,t)
constexpr int kNBT = kB * kT;            // 2
constexpr int kNI = kNBT * kV;           // 6 render instances
constexpr int kH = 224, kW = 448;
constexpr int kHW = kH * kW;             // 100352
constexpr int kCX = kW + 4;              // 452 cells in x  (x0 in [-2, 449])
constexpr int kCY = kH + 4;              // 228 cells in y  (y0 in [-2, 225])
constexpr int kNCELL = kCX * kCY;
constexpr int kMaxEnt = kNI * kNG;       // 36864

// output bases (floats)
constexpr size_t RGB_SZ = (size_t)kNI * 3 * kHW;   // 1806336
constexpr size_t A_SZ   = (size_t)kNI * kHW;       // 602112
constexpr size_t O_RGB_STA = 0;
constexpr size_t O_RGB_DYN = O_RGB_STA + RGB_SZ;
constexpr size_t O_RGB_ALL = O_RGB_DYN + RGB_SZ;
constexpr size_t O_A_STA   = O_RGB_ALL + RGB_SZ;   // 5419008
constexpr size_t O_A_DYN   = O_A_STA + A_SZ;
constexpr size_t O_A_ALL   = O_A_DYN + A_SZ;
constexpr size_t O_SEM     = O_A_ALL + A_SZ;       // 7225344
constexpr size_t O_SM      = O_SEM + A_SZ;         // 7827456
constexpr size_t O_TR      = O_SM + 1;

// workspace layout (bytes)
constexpr size_t WS_W2C   = 0;                       // 6*16 floats
constexpr size_t WS_CNTR  = 512;                     // entCnt(int) @512, sigmaSum f32[6] @528,
                                                     // cnt i32[6] @560, touch i32[6] @592
constexpr size_t WS_HEADS = 1024;                    // kNI*kNCELL ints = 2,473,344 B
constexpr size_t WS_ENTZ  = WS_HEADS + (size_t)kNI * kNCELL * 4;   // 2,474,368
constexpr size_t WS_ENTG  = WS_ENTZ + (size_t)kMaxEnt * 4;
constexpr size_t WS_ENTNX = WS_ENTG + (size_t)kMaxEnt * 4;
constexpr size_t WS_PAY   = WS_ENTNX + (size_t)kMaxEnt * 4;        // 36864*12 floats (48B/entry)

__device__ __forceinline__ float clip01(float x) { return fminf(fmaxf(x, 0.f), 1.f); }
}

// ---------------- kernels ----------------

// invert the 6 camera_to_world matrices (Gauss-Jordan w/ partial pivot)
__global__ void k_inv(const float* __restrict__ c2w, float* __restrict__ w2c) {
    int i = threadIdx.x;
    if (i >= kNI) return;
    float m[4][8];
    const float* A = c2w + (size_t)i * 16;
    for (int r = 0; r < 4; ++r)
        for (int c = 0; c < 4; ++c) { m[r][c] = A[r * 4 + c]; m[r][c + 4] = (r == c) ? 1.f : 0.f; }
    for (int col = 0; col < 4; ++col) {
        int piv = col; float mx = fabsf(m[col][col]);
        for (int r = col + 1; r < 4; ++r) { float a = fabsf(m[r][col]); if (a > mx) { mx = a; piv = r; } }
        if (piv != col)
            for (int c = 0; c < 8; ++c) { float t = m[col][c]; m[col][c] = m[piv][c]; m[piv][c] = t; }
        float inv = 1.f / m[col][col];
        for (int c = 0; c < 8; ++c) m[col][c] *= inv;
        for (int r = 0; r < 4; ++r) {
            if (r == col) continue;
            float f = m[r][col];
            for (int c = 0; c < 8; ++c) m[r][c] -= f * m[col][c];
        }
    }
    for (int r = 0; r < 4; ++r)
        for (int c = 0; c < 4; ++c) w2c[(size_t)i * 16 + r * 4 + c] = m[r][c + 4];
}

// project every (instance, gaussian), bin into per-cell linked lists, accumulate sigma stats
__global__ void k_pre(const float* __restrict__ centers, const float* __restrict__ scale,
                      const float* __restrict__ feat, const float* __restrict__ opac,
                      const float* __restrict__ bgp, const float* __restrict__ intr,
                      const float* __restrict__ fpose, const float* __restrict__ w2c_all,
                      int* __restrict__ heads, int* __restrict__ entCnt,
                      float* __restrict__ entZ, int* __restrict__ entG, int* __restrict__ entNext,
                      float* __restrict__ pay, float* __restrict__ sigmaSum, int* __restrict__ cnt) {
    int g = blockIdx.x * blockDim.x + threadIdx.x;
    int inst = blockIdx.y;
    if (g >= kNG) return;
    int bt = inst / kV, v = inst % kV;
    int b = bt / kT;

    const float* c = centers + ((size_t)bt * kNG + g) * 3;
    float c0 = c[0], c1 = c[1], c2 = c[2];
    const float* P = fpose + (size_t)b * 16;
    float wx[4];
#pragma unroll
    for (int i = 0; i < 4; ++i)
        wx[i] = P[i * 4 + 0] * c0 + P[i * 4 + 1] * c1 + P[i * 4 + 2] * c2 + P[i * 4 + 3];

    const float* M = w2c_all + (size_t)inst * 16;
    float camx = M[0] * wx[0] + M[1] * wx[1] + M[2] * wx[2] + M[3] * wx[3];
    float camy = M[4] * wx[0] + M[5] * wx[1] + M[6] * wx[2] + M[7] * wx[3];
    float camz = M[8] * wx[0] + M[9] * wx[1] + M[10] * wx[2] + M[11] * wx[3];

    float op = clip01(opac[(size_t)bt * kNG + g]);
    bool zok = (camz > 0.001f) && isfinite(camx) && isfinite(camy) && isfinite(camz);
    if (!zok || op <= 1e-5f) return;   // invalid in ALL branches (a_dyn,a_sta <= op)

    const float* it = intr + ((size_t)b * kV + v) * 4;
    float fx = it[0], fy = it[1], cx = it[2], cy = it[3];
    float u = camx * fx / camz + cx;
    float vv = camy * fy / camz + cy;

    const float* sp = scale + ((size_t)bt * kNG + g) * 3;
    float sf = (sp[0] + sp[1] + sp[2]) / 3.f;
    float sg = fminf(fmaxf((fx + fy) * 0.5f * fabsf(sf) / fmaxf(camz, 0.001f), 0.75f), 10.f);

    // inb (reference margins): u in [-3, W+2], v in [-3, H+2]
    bool inb = (u >= -3.f) && (u <= (float)kW + 2.f) && (vv >= -3.f) && (vv <= (float)kH + 2.f);
    if (!inb) return;

    // 'all'-branch stats (valid == reached here)
    atomicAdd(&sigmaSum[inst], sg);
    atomicAdd(&cnt[inst], 1);

    int x0 = (int)floorf(u);
    int y0 = (int)floorf(vv);
    // footprint touches in-bounds pixels only if x0 in [-2, W+1], y0 in [-2, H+1]
    if (x0 < -2 || x0 > kW + 1 || y0 < -2 || y0 > kH + 1) return;

    float bg = bgp[(size_t)bt * kNG + g];
    float dyn = clip01(1.f - bg);
    float aAll = op;
    float aDyn = clip01(op * dyn);
    float aSta = clip01(op * (1.f - dyn));
    if (aDyn <= 1e-5f) aDyn = 0.f;     // reference drops these gaussians in that branch
    if (aSta <= 1e-5f) aSta = 0.f;

    const float* fc = feat + ((size_t)bt * kNG + g) * 3;
    float r = clip01(fc[0]), gc = clip01(fc[1]), bcl = clip01(fc[2]);

    int e = atomicAdd(entCnt, 1);
    entZ[e] = camz;
    entG[e] = g;
    float* p = pay + (size_t)e * 12;
    p[0] = u; p[1] = vv; p[2] = 1.f / fmaxf(sg, 0.001f);
    p[3] = aSta; p[4] = aDyn; p[5] = aAll;
    p[6] = r; p[7] = gc; p[8] = bcl; p[9] = 0.f; p[10] = 0.f; p[11] = 0.f;

    int cell = inst * kNCELL + (y0 + 2) * kCX + (x0 + 2);
    entNext[e] = atomicExch(&heads[cell], e);
}

// per-pixel ordered compositing for all three branches
__global__ void k_px(const int* __restrict__ heads, const float* __restrict__ entZ,
                     const int* __restrict__ entG, const int* __restrict__ entNext,
                     const float* __restrict__ pay, float* __restrict__ out,
                     int* __restrict__ touch) {
    int pix = blockIdx.x * blockDim.x + threadIdx.x;
    int inst = blockIdx.y;
    if (pix >= kHW) return;
    int py = pix / kW, px = pix % kW;
    const int* hb = heads + (size_t)inst * kNCELL;

    float ad0 = 0.f, ad1 = 0.f, ad2 = 0.f;
    float r0 = 0.f, g0 = 0.f, b0 = 0.f;
    float r1 = 0.f, g1 = 0.f, b1 = 0.f;
    float r2 = 0.f, g2 = 0.f, b2 = 0.f;

    float lastZ = -1e30f; int lastG = -1;
    for (;;) {
        // select next contributor: min (z,g) strictly greater than (lastZ,lastG)
        float bz = 1e30f; int bgi = 0x7fffffff; int be = -1;
        for (int dy = 0; dy < 5; ++dy) {
            const int* hrow = hb + (size_t)(py + dy) * kCX + px;
#pragma unroll
            for (int dx = 0; dx < 5; ++dx) {
                int e = hrow[dx];
                while (e >= 0) {
                    float z = entZ[e]; int gi = entG[e];
                    bool gt = (z > lastZ) || (z == lastZ && gi > lastG);
                    bool lt = (z < bz) || (z == bz && gi < bgi);
                    if (gt && lt) { bz = z; bgi = gi; be = e; }
                    e = entNext[e];
                }
            }
        }
        if (be < 0) break;

        const float4* pp = (const float4*)(pay + (size_t)be * 12);
        float4 q0 = pp[0];   // u, v, invss, aSta
        float4 q1 = pp[1];   // aDyn, aAll, colR, colG
        float4 q2 = pp[2];   // colB, -, -, -
        float du = (q0.x - (float)px) * q0.z;
        float dv = (q0.y - (float)py) * q0.z;
        float lb = expf(-0.5f * (du * du + dv * dv));

        float la, Tt, ct;
        // sta
        la = fminf(lb * q0.w, 0.999f);
        Tt = clip01(1.f - ad0); ct = la * Tt;
        ad0 = fminf(ad0 + ct, 0.999f);
        r0 += q1.z * ct; g0 += q1.w * ct; b0 += q2.x * ct;
        // dyn
        la = fminf(lb * q1.x, 0.999f);
        Tt = clip01(1.f - ad1); ct = la * Tt;
        ad1 = fminf(ad1 + ct, 0.999f);
        r1 += q1.z * ct; g1 += q1.w * ct; b1 += q2.x * ct;
        // all
        la = fminf(lb * q1.y, 0.999f);
        Tt = clip01(1.f - ad2); ct = la * Tt;
        ad2 = fminf(ad2 + ct, 0.999f);
        r2 += q1.z * ct; g2 += q1.w * ct; b2 += q2.x * ct;

        lastZ = bz; lastG = bgi;
    }

    size_t o = (size_t)pix;
    size_t ib3 = (size_t)inst * 3;
    out[O_RGB_STA + (ib3 + 0) * kHW + o] = clip01(r0);
    out[O_RGB_STA + (ib3 + 1) * kHW + o] = clip01(g0);
    out[O_RGB_STA + (ib3 + 2) * kHW + o] = clip01(b0);
    out[O_RGB_DYN + (ib3 + 0) * kHW + o] = clip01(r1);
    out[O_RGB_DYN + (ib3 + 1) * kHW + o] = clip01(g1);
    out[O_RGB_DYN + (ib3 + 2) * kHW + o] = clip01(b1);
    out[O_RGB_ALL + (ib3 + 0) * kHW + o] = clip01(r2);
    out[O_RGB_ALL + (ib3 + 1) * kHW + o] = clip01(g2);
    out[O_RGB_ALL + (ib3 + 2) * kHW + o] = clip01(b2);
    out[O_A_STA + (size_t)inst * kHW + o] = ad0;   // already in [0, 0.999]
    out[O_A_DYN + (size_t)inst * kHW + o] = ad1;
    out[O_A_ALL + (size_t)inst * kHW + o] = ad2;

    if (ad2 > 1e-6f) atomicAdd(&touch[inst], 1);
}

__global__ void k_fin(const float* __restrict__ sigmaSum, const int* __restrict__ cnt,
                      const int* __restrict__ touch, float* __restrict__ out) {
    if (threadIdx.x == 0 && blockIdx.x == 0) {
        float sm = 0.f, tr = 0.f;
        for (int i = 0; i < kNI; ++i) {
            sm += sigmaSum[i] / fmaxf((float)cnt[i], 1.f);
            tr += (float)touch[i] / (float)kHW;
        }
        out[O_SM] = sm / (float)kNI;
        out[O_TR] = tr / (float)kNI;
    }
}

// ---------------- launch ----------------
extern "C" void kernel_launch(void* const* d_in, const int* in_sizes, int n_in,
                              void* d_out, int out_size, void* d_ws, size_t ws_size,
                              hipStream_t stream) {
    const float* centers = (const float*)d_in[0];
    const float* scal    = (const float*)d_in[1];
    const float* feat    = (const float*)d_in[2];
    const float* opac    = (const float*)d_in[3];
    const float* bgp     = (const float*)d_in[4];
    const float* sem     = (const float*)d_in[5];
    const float* intr    = (const float*)d_in[6];
    const float* c2w     = (const float*)d_in[7];
    const float* fpose   = (const float*)d_in[8];
    float* out = (float*)d_out;
    char* ws = (char*)d_ws;

    float* w2c      = (float*)(ws + WS_W2C);
    int*   entCnt   = (int*)(ws + WS_CNTR);
    float* sigmaSum = (float*)(ws + WS_CNTR + 16);
    int*   cnt      = (int*)(ws + WS_CNTR + 48);
    int*   touch    = (int*)(ws + WS_CNTR + 80);
    int*   heads    = (int*)(ws + WS_HEADS);
    float* entZ     = (float*)(ws + WS_ENTZ);
    int*   entG     = (int*)(ws + WS_ENTG);
    int*   entNext  = (int*)(ws + WS_ENTNX);
    float* pay      = (float*)(ws + WS_PAY);

    hipMemsetAsync(ws + WS_CNTR, 0, 128, stream);
    hipMemsetAsync(ws + WS_HEADS, 0xFF, (size_t)kNI * kNCELL * 4, stream);

    k_inv<<<1, 64, 0, stream>>>(c2w, w2c);

    dim3 gpre((kNG + 255) / 256, kNI);
    k_pre<<<gpre, 256, 0, stream>>>(centers, scal, feat, opac, bgp, intr, fpose, w2c,
                                    heads, entCnt, entZ, entG, entNext, pay, sigmaSum, cnt);

    dim3 gpx((kHW + 255) / 256, kNI);
    k_px<<<gpx, 256, 0, stream>>>(heads, entZ, entG, entNext, pay, out, touch);

    hipMemcpyAsync(out + O_SEM, sem, (size_t)kNI * kHW * sizeof(float),
                   hipMemcpyDeviceToDevice, stream);

    k_fin<<<1, 1, 0, stream>>>(sigmaSum, cnt, touch, out);
}

// Round 2
// 199.403 us; speedup vs baseline: 1.1660x; 1.1660x over previous
//
#include <hip/hip_runtime.h>
#include <hip/hip_bf16.h>

// ---------------- problem constants ----------------
namespace {
constexpr int kB = 1, kT = 2, kV = 3;
constexpr int kGH = 32, kGW = 64;
constexpr int kNG = kV * kGH * kGW;      // 6144 gaussians per (b,t)
constexpr int kNBT = kB * kT;            // 2
constexpr int kNI = kNBT * kV;           // 6 render instances
constexpr int kH = 224, kW = 448;
constexpr int kHW = kH * kW;             // 100352
constexpr int kCX = kW + 4;              // 452 cells in x  (x0 in [-2, 449])
constexpr int kCY = kH + 4;              // 228 cells in y
constexpr int kNCELL = kCX * kCY;        // 103056
constexpr int kNTOT = kNI * kNCELL;      // 618336 cells total
constexpr int kMaxEnt = kNI * kNG;       // 36864
constexpr int kNBScan = (kNTOT + 255) / 256;  // 2416

// output bases (floats)
constexpr size_t RGB_SZ = (size_t)kNI * 3 * kHW;
constexpr size_t A_SZ   = (size_t)kNI * kHW;
constexpr size_t O_RGB_STA = 0;
constexpr size_t O_RGB_DYN = O_RGB_STA + RGB_SZ;
constexpr size_t O_RGB_ALL = O_RGB_DYN + RGB_SZ;
constexpr size_t O_A_STA   = O_RGB_ALL + RGB_SZ;
constexpr size_t O_A_DYN   = O_A_STA + A_SZ;
constexpr size_t O_A_ALL   = O_A_DYN + A_SZ;
constexpr size_t O_SEM     = O_A_ALL + A_SZ;
constexpr size_t O_SM      = O_SEM + A_SZ;
constexpr size_t O_TR      = O_SM + 1;

// workspace layout (bytes)
constexpr size_t WS_W2C   = 0;                                      // 6*16 f32
constexpr size_t WS_CNTR  = 512;   // entCnt @512, sigmaSum[6] @528, cnt[6] @560, touch[6] @592
constexpr size_t WS_CCNT  = 1024;                                   // int[kNTOT]
constexpr size_t WS_COFF  = WS_CCNT + (size_t)kNTOT * 4;            // int[kNTOT+1]
constexpr size_t WS_BSUM  = WS_COFF + (size_t)(kNTOT + 1) * 4 + 12; // int[kNBScan]
constexpr size_t WS_ECEL  = WS_BSUM + (size_t)kNBScan * 4;          // int[kMaxEnt]
constexpr size_t WS_EZ    = WS_ECEL + (size_t)kMaxEnt * 4;          // f32[kMaxEnt]
constexpr size_t WS_EG    = WS_EZ + (size_t)kMaxEnt * 4;            // int[kMaxEnt]
constexpr size_t WS_PAY   = WS_EG + (size_t)kMaxEnt * 4;            // f32[12*kMaxEnt]
constexpr size_t WS_SZG   = WS_PAY + (size_t)kMaxEnt * 48;          // int2[kMaxEnt]
// total ~7.5 MB

__device__ __forceinline__ float clip01(float x) { return fminf(fmaxf(x, 0.f), 1.f); }
}

// ---------------- kernels ----------------

__global__ void k_inv(const float* __restrict__ c2w, float* __restrict__ w2c) {
    int i = threadIdx.x;
    if (i >= kNI) return;
    float m[4][8];
    const float* A = c2w + (size_t)i * 16;
    for (int r = 0; r < 4; ++r)
        for (int c = 0; c < 4; ++c) { m[r][c] = A[r * 4 + c]; m[r][c + 4] = (r == c) ? 1.f : 0.f; }
    for (int col = 0; col < 4; ++col) {
        int piv = col; float mx = fabsf(m[col][col]);
        for (int r = col + 1; r < 4; ++r) { float a = fabsf(m[r][col]); if (a > mx) { mx = a; piv = r; } }
        if (piv != col)
            for (int c = 0; c < 8; ++c) { float t = m[col][c]; m[col][c] = m[piv][c]; m[piv][c] = t; }
        float inv = 1.f / m[col][col];
        for (int c = 0; c < 8; ++c) m[col][c] *= inv;
        for (int r = 0; r < 4; ++r) {
            if (r == col) continue;
            float f = m[r][col];
            for (int c = 0; c < 8; ++c) m[r][c] -= f * m[col][c];
        }
    }
    for (int r = 0; r < 4; ++r)
        for (int c = 0; c < 4; ++c) w2c[(size_t)i * 16 + r * 4 + c] = m[r][c + 4];
}

// project, stage entries, count per cell
__global__ void k_pre(const float* __restrict__ centers, const float* __restrict__ scale,
                      const float* __restrict__ feat, const float* __restrict__ opac,
                      const float* __restrict__ bgp, const float* __restrict__ intr,
                      const float* __restrict__ fpose, const float* __restrict__ w2c_all,
                      int* __restrict__ cellCnt, int* __restrict__ entCnt,
                      int* __restrict__ entCell, float* __restrict__ entZ, int* __restrict__ entG,
                      float* __restrict__ pay, float* __restrict__ sigmaSum, int* __restrict__ cnt) {
    int g = blockIdx.x * blockDim.x + threadIdx.x;
    int inst = blockIdx.y;
    if (g >= kNG) return;
    int bt = inst / kV, v = inst % kV;
    int b = bt / kT;

    const float* c = centers + ((size_t)bt * kNG + g) * 3;
    float c0 = c[0], c1 = c[1], c2 = c[2];
    const float* P = fpose + (size_t)b * 16;
    float wx[4];
#pragma unroll
    for (int i = 0; i < 4; ++i)
        wx[i] = P[i * 4 + 0] * c0 + P[i * 4 + 1] * c1 + P[i * 4 + 2] * c2 + P[i * 4 + 3];

    const float* M = w2c_all + (size_t)inst * 16;
    float camx = M[0] * wx[0] + M[1] * wx[1] + M[2] * wx[2] + M[3] * wx[3];
    float camy = M[4] * wx[0] + M[5] * wx[1] + M[6] * wx[2] + M[7] * wx[3];
    float camz = M[8] * wx[0] + M[9] * wx[1] + M[10] * wx[2] + M[11] * wx[3];

    float op = clip01(opac[(size_t)bt * kNG + g]);
    bool zok = (camz > 0.001f) && isfinite(camx) && isfinite(camy) && isfinite(camz);
    if (!zok || op <= 1e-5f) return;

    const float* it = intr + ((size_t)b * kV + v) * 4;
    float fx = it[0], fy = it[1], cx = it[2], cy = it[3];
    float u = camx * fx / camz + cx;
    float vv = camy * fy / camz + cy;

    const float* sp = scale + ((size_t)bt * kNG + g) * 3;
    float sf = (sp[0] + sp[1] + sp[2]) / 3.f;
    float sg = fminf(fmaxf((fx + fy) * 0.5f * fabsf(sf) / fmaxf(camz, 0.001f), 0.75f), 10.f);

    bool inb = (u >= -3.f) && (u <= (float)kW + 2.f) && (vv >= -3.f) && (vv <= (float)kH + 2.f);
    if (!inb) return;

    atomicAdd(&sigmaSum[inst], sg);
    atomicAdd(&cnt[inst], 1);

    int x0 = (int)floorf(u);
    int y0 = (int)floorf(vv);
    if (x0 < -2 || x0 > kW + 1 || y0 < -2 || y0 > kH + 1) return;

    float bg = bgp[(size_t)bt * kNG + g];
    float dyn = clip01(1.f - bg);
    float aAll = op;
    float aDyn = clip01(op * dyn);
    float aSta = clip01(op * (1.f - dyn));
    if (aDyn <= 1e-5f) aDyn = 0.f;
    if (aSta <= 1e-5f) aSta = 0.f;

    const float* fc = feat + ((size_t)bt * kNG + g) * 3;
    float r = clip01(fc[0]), gc = clip01(fc[1]), bcl = clip01(fc[2]);

    int e = atomicAdd(entCnt, 1);
    entZ[e] = camz;
    entG[e] = g;
    int cell = inst * kNCELL + (y0 + 2) * kCX + (x0 + 2);
    entCell[e] = cell;
    atomicAdd(&cellCnt[cell], 1);

    float* p = pay + (size_t)e * 12;
    p[0] = u; p[1] = vv; p[2] = 1.f / fmaxf(sg, 0.001f);
    p[3] = aSta; p[4] = aDyn; p[5] = aAll;
    p[6] = r; p[7] = gc; p[8] = bcl; p[9] = 0.f; p[10] = 0.f; p[11] = 0.f;
}

// --- prefix sum (3 stages) ---
__global__ void k_scan1(const int* __restrict__ cellCnt, int* __restrict__ cellOff,
                        int* __restrict__ blockSum) {
    __shared__ int sh[256];
    int t = threadIdx.x;
    int idx = blockIdx.x * 256 + t;
    int v = (idx < kNTOT) ? cellCnt[idx] : 0;
    sh[t] = v; __syncthreads();
    for (int o = 1; o < 256; o <<= 1) {
        int x = (t >= o) ? sh[t - o] : 0;
        __syncthreads(); sh[t] += x; __syncthreads();
    }
    if (idx < kNTOT) cellOff[idx] = sh[t] - v;
    if (t == 255) blockSum[blockIdx.x] = sh[255];
}

__global__ void k_scan2(int* __restrict__ blockSum, int* __restrict__ cellOff) {
    __shared__ int sh[256];
    int t = threadIdx.x;
    int run = 0;
    for (int chunk = 0; chunk < kNBScan; chunk += 256) {
        int i = chunk + t;
        int v = (i < kNBScan) ? blockSum[i] : 0;
        __syncthreads();
        sh[t] = v; __syncthreads();
        for (int o = 1; o < 256; o <<= 1) {
            int x = (t >= o) ? sh[t - o] : 0;
            __syncthreads(); sh[t] += x; __syncthreads();
        }
        if (i < kNBScan) blockSum[i] = run + sh[t] - v;
        run += sh[255];
    }
    if (t == 0) cellOff[kNTOT] = run;
}

__global__ void k_scan3(int* __restrict__ cellOff, const int* __restrict__ blockSum) {
    int idx = blockIdx.x * 256 + threadIdx.x;
    if (idx < kNTOT) cellOff[idx] += blockSum[idx >> 8];
}

// place entries into compact per-cell arrays (consumes cellCnt back to zero)
__global__ void k_scatter(const int* __restrict__ entCnt, const int* __restrict__ entCell,
                          const float* __restrict__ entZ, const int* __restrict__ entG,
                          const int* __restrict__ cellOff, int* __restrict__ cellCnt,
                          int2* __restrict__ szg) {
    int e = blockIdx.x * 256 + threadIdx.x;
    if (e >= entCnt[0]) return;
    int cell = entCell[e];
    int pos = cellOff[cell] + atomicSub(&cellCnt[cell], 1) - 1;
    szg[pos] = make_int2(__float_as_int(entZ[e]), (entG[e] << 16) | e);
}

// per-pixel ordered compositing over 5 contiguous ranges
__global__ void k_px(const int* __restrict__ off, const int2* __restrict__ szg,
                     const float* __restrict__ pay, float* __restrict__ out,
                     int* __restrict__ touch) {
    int pix = blockIdx.x * blockDim.x + threadIdx.x;
    int inst = blockIdx.y;
    if (pix >= kHW) return;
    int py = pix / kW, px = pix - py * kW;
    int base = inst * kNCELL + py * kCX + px;

    int rs[5], re[5], total = 0;
#pragma unroll
    for (int dy = 0; dy < 5; ++dy) {
        int c = base + dy * kCX;
        rs[dy] = off[c];
        re[dy] = off[c + 5];
        total += re[dy] - rs[dy];
    }

    float ad0 = 0.f, ad1 = 0.f, ad2 = 0.f;
    float r0 = 0.f, g0 = 0.f, b0 = 0.f;
    float r1 = 0.f, g1 = 0.f, b1 = 0.f;
    float r2 = 0.f, g2 = 0.f, b2 = 0.f;

    if (total > 0) {
        float lastZ = -1e30f; int lastK = -1;
        float fpx = (float)px, fpy = (float)py;
        for (int it = 0; it < total; ++it) {
            // select next in (z, key) order
            float bz = 1e30f; int bk = 0x7fffffff;
#pragma unroll
            for (int dy = 0; dy < 5; ++dy) {
                for (int e = rs[dy]; e < re[dy]; ++e) {
                    int2 zk = szg[e];
                    float z = __int_as_float(zk.x);
                    int k = zk.y;
                    bool gt = (z > lastZ) || (z == lastZ && k > lastK);
                    bool lt = (z < bz) || (z == bz && k < bk);
                    if (gt && lt) { bz = z; bk = k; }
                }
            }
            lastZ = bz; lastK = bk;
            int e = bk & 0xFFFF;

            const float4* pp = (const float4*)(pay + (size_t)e * 12);
            float4 q0 = pp[0];   // u, v, invss, aSta
            float4 q1 = pp[1];   // aDyn, aAll, colR, colG
            float4 q2 = pp[2];   // colB, -, -, -
            float du = (q0.x - fpx) * q0.z;
            float dv = (q0.y - fpy) * q0.z;
            float lb = expf(-0.5f * (du * du + dv * dv));

            float la, Tt, ct;
            la = fminf(lb * q0.w, 0.999f);
            Tt = clip01(1.f - ad0); ct = la * Tt;
            ad0 = fminf(ad0 + ct, 0.999f);
            r0 += q1.z * ct; g0 += q1.w * ct; b0 += q2.x * ct;

            la = fminf(lb * q1.x, 0.999f);
            Tt = clip01(1.f - ad1); ct = la * Tt;
            ad1 = fminf(ad1 + ct, 0.999f);
            r1 += q1.z * ct; g1 += q1.w * ct; b1 += q2.x * ct;

            la = fminf(lb * q1.y, 0.999f);
            Tt = clip01(1.f - ad2); ct = la * Tt;
            ad2 = fminf(ad2 + ct, 0.999f);
            r2 += q1.z * ct; g2 += q1.w * ct; b2 += q2.x * ct;
        }
    }

    size_t o = (size_t)pix;
    size_t ib3 = (size_t)inst * 3;
    out[O_RGB_STA + (ib3 + 0) * kHW + o] = clip01(r0);
    out[O_RGB_STA + (ib3 + 1) * kHW + o] = clip01(g0);
    out[O_RGB_STA + (ib3 + 2) * kHW + o] = clip01(b0);
    out[O_RGB_DYN + (ib3 + 0) * kHW + o] = clip01(r1);
    out[O_RGB_DYN + (ib3 + 1) * kHW + o] = clip01(g1);
    out[O_RGB_DYN + (ib3 + 2) * kHW + o] = clip01(b1);
    out[O_RGB_ALL + (ib3 + 0) * kHW + o] = clip01(r2);
    out[O_RGB_ALL + (ib3 + 1) * kHW + o] = clip01(g2);
    out[O_RGB_ALL + (ib3 + 2) * kHW + o] = clip01(b2);
    out[O_A_STA + (size_t)inst * kHW + o] = ad0;
    out[O_A_DYN + (size_t)inst * kHW + o] = ad1;
    out[O_A_ALL + (size_t)inst * kHW + o] = ad2;

    if (ad2 > 1e-6f) atomicAdd(&touch[inst], 1);
}

__global__ void k_fin(const float* __restrict__ sigmaSum, const int* __restrict__ cnt,
                      const int* __restrict__ touch, float* __restrict__ out) {
    if (threadIdx.x == 0 && blockIdx.x == 0) {
        float sm = 0.f, tr = 0.f;
        for (int i = 0; i < kNI; ++i) {
            sm += sigmaSum[i] / fmaxf((float)cnt[i], 1.f);
            tr += (float)touch[i] / (float)kHW;
        }
        out[O_SM] = sm / (float)kNI;
        out[O_TR] = tr / (float)kNI;
    }
}

// ---------------- launch ----------------
extern "C" void kernel_launch(void* const* d_in, const int* in_sizes, int n_in,
                              void* d_out, int out_size, void* d_ws, size_t ws_size,
                              hipStream_t stream) {
    const float* centers = (const float*)d_in[0];
    const float* scal    = (const float*)d_in[1];
    const float* feat    = (const float*)d_in[2];
    const float* opac    = (const float*)d_in[3];
    const float* bgp     = (const float*)d_in[4];
    const float* sem     = (const float*)d_in[5];
    const float* intr    = (const float*)d_in[6];
    const float* c2w     = (const float*)d_in[7];
    const float* fpose   = (const float*)d_in[8];
    float* out = (float*)d_out;
    char* ws = (char*)d_ws;

    float* w2c      = (float*)(ws + WS_W2C);
    int*   entCnt   = (int*)(ws + WS_CNTR);
    float* sigmaSum = (float*)(ws + WS_CNTR + 16);
    int*   cnt      = (int*)(ws + WS_CNTR + 48);
    int*   touch    = (int*)(ws + WS_CNTR + 80);
    int*   cellCnt  = (int*)(ws + WS_CCNT);
    int*   cellOff  = (int*)(ws + WS_COFF);
    int*   blockSum = (int*)(ws + WS_BSUM);
    int*   entCell  = (int*)(ws + WS_ECEL);
    float* entZ     = (float*)(ws + WS_EZ);
    int*   entG     = (int*)(ws + WS_EG);
    float* pay      = (float*)(ws + WS_PAY);
    int2*  szg      = (int2*)(ws + WS_SZG);

    hipMemsetAsync(ws + WS_CNTR, 0, 128, stream);
    hipMemsetAsync(ws + WS_CCNT, 0, (size_t)kNTOT * 4, stream);

    k_inv<<<1, 64, 0, stream>>>(c2w, w2c);

    dim3 gpre((kNG + 255) / 256, kNI);
    k_pre<<<gpre, 256, 0, stream>>>(centers, scal, feat, opac, bgp, intr, fpose, w2c,
                                    cellCnt, entCnt, entCell, entZ, entG, pay, sigmaSum, cnt);

    k_scan1<<<kNBScan, 256, 0, stream>>>(cellCnt, cellOff, blockSum);
    k_scan2<<<1, 256, 0, stream>>>(blockSum, cellOff);
    k_scan3<<<kNBScan, 256, 0, stream>>>(cellOff, blockSum);

    k_scatter<<<(kMaxEnt + 255) / 256, 256, 0, stream>>>(entCnt, entCell, entZ, entG,
                                                         cellOff, cellCnt, szg);

    dim3 gpx((kHW + 255) / 256, kNI);
    k_px<<<gpx, 256, 0, stream>>>(cellOff, szg, pay, out, touch);

    hipMemcpyAsync(out + O_SEM, sem, (size_t)kNI * kHW * sizeof(float),
                   hipMemcpyDeviceToDevice, stream);

    k_fin<<<1, 1, 0, stream>>>(sigmaSum, cnt, touch, out);
}

// Round 4
// 189.797 us; speedup vs baseline: 1.2250x; 1.0506x over previous
//
#include <hip/hip_runtime.h>
#include <hip/hip_bf16.h>

// ---------------- problem constants ----------------
namespace {
constexpr int kB = 1, kT = 2, kV = 3;
constexpr int kGH = 32, kGW = 64;
constexpr int kNG = kV * kGH * kGW;      // 6144 gaussians per (b,t)
constexpr int kNBT = kB * kT;            // 2
constexpr int kNI = kNBT * kV;           // 6 render instances
constexpr int kH = 224, kW = 448;
constexpr int kHW = kH * kW;             // 100352 (= 392 * 256 exactly)
constexpr int kCX = kW + 4;              // 452 cells in x
constexpr int kCY = kH + 4;              // 228 cells in y
constexpr int kNCELL = kCX * kCY;        // 103056
constexpr int kNTOT = kNI * kNCELL;      // 618336
constexpr int kMaxEnt = kNI * kNG;       // 36864
constexpr int kNBScan = (kNTOT + 255) / 256;  // 2416

// output bases (floats)
constexpr size_t RGB_SZ = (size_t)kNI * 3 * kHW;
constexpr size_t A_SZ   = (size_t)kNI * kHW;
constexpr size_t O_RGB_STA = 0;
constexpr size_t O_RGB_DYN = O_RGB_STA + RGB_SZ;
constexpr size_t O_RGB_ALL = O_RGB_DYN + RGB_SZ;
constexpr size_t O_A_STA   = O_RGB_ALL + RGB_SZ;
constexpr size_t O_A_DYN   = O_A_STA + A_SZ;
constexpr size_t O_A_ALL   = O_A_DYN + A_SZ;
constexpr size_t O_SEM     = O_A_ALL + A_SZ;
constexpr size_t O_SM      = O_SEM + A_SZ;
constexpr size_t O_TR      = O_SM + 1;

// workspace layout (bytes) — identical to the round-2 (passed) layout, no aliasing
constexpr size_t WS_W2C   = 0;                                      // 6*16 f32
constexpr size_t WS_CNTR  = 512;   // entCnt @+0, sigmaSum[6] @+16, cnt[6] @+48, touch[6] @+80
constexpr size_t WS_CCNT  = 1024;                                   // int[kNTOT]
constexpr size_t WS_COFF  = WS_CCNT + (size_t)kNTOT * 4;            // int[kNTOT+1]
constexpr size_t WS_BSUM  = WS_COFF + (size_t)(kNTOT + 1) * 4 + 12; // int[kNBScan]
constexpr size_t WS_ECEL  = WS_BSUM + (size_t)kNBScan * 4;          // int[kMaxEnt]
constexpr size_t WS_EZ    = WS_ECEL + (size_t)kMaxEnt * 4;          // f32[kMaxEnt]
constexpr size_t WS_EG    = WS_EZ + (size_t)kMaxEnt * 4;            // int[kMaxEnt]
constexpr size_t WS_PAY   = WS_EG + (size_t)kMaxEnt * 4;            // f32[12*kMaxEnt]
constexpr size_t WS_SZG   = WS_PAY + (size_t)kMaxEnt * 48;          // int2[kMaxEnt]
// end ~7.46 MB (proven to fit in round 2)

__device__ __forceinline__ float clip01(float x) { return fminf(fmaxf(x, 0.f), 1.f); }
__device__ __forceinline__ unsigned long long packkey(int zbits, int ikey) {
    return ((unsigned long long)(unsigned)zbits << 32) | (unsigned)ikey;
}
}

// ---------------- kernels ----------------

__global__ void k_inv(const float* __restrict__ c2w, float* __restrict__ w2c) {
    int i = threadIdx.x;
    if (i >= kNI) return;
    float m[4][8];
    const float* A = c2w + (size_t)i * 16;
    for (int r = 0; r < 4; ++r)
        for (int c = 0; c < 4; ++c) { m[r][c] = A[r * 4 + c]; m[r][c + 4] = (r == c) ? 1.f : 0.f; }
    for (int col = 0; col < 4; ++col) {
        int piv = col; float mx = fabsf(m[col][col]);
        for (int r = col + 1; r < 4; ++r) { float a = fabsf(m[r][col]); if (a > mx) { mx = a; piv = r; } }
        if (piv != col)
            for (int c = 0; c < 8; ++c) { float t = m[col][c]; m[col][c] = m[piv][c]; m[piv][c] = t; }
        float inv = 1.f / m[col][col];
        for (int c = 0; c < 8; ++c) m[col][c] *= inv;
        for (int r = 0; r < 4; ++r) {
            if (r == col) continue;
            float f = m[r][col];
            for (int c = 0; c < 8; ++c) m[r][c] -= f * m[col][c];
        }
    }
    for (int r = 0; r < 4; ++r)
        for (int c = 0; c < 4; ++c) w2c[(size_t)i * 16 + r * 4 + c] = m[r][c + 4];
}

// project, stage entries, count per cell (verbatim round-2)
__global__ void k_pre(const float* __restrict__ centers, const float* __restrict__ scale,
                      const float* __restrict__ feat, const float* __restrict__ opac,
                      const float* __restrict__ bgp, const float* __restrict__ intr,
                      const float* __restrict__ fpose, const float* __restrict__ w2c_all,
                      int* __restrict__ cellCnt, int* __restrict__ entCnt,
                      int* __restrict__ entCell, float* __restrict__ entZ, int* __restrict__ entG,
                      float* __restrict__ pay, float* __restrict__ sigmaSum, int* __restrict__ cnt) {
    int g = blockIdx.x * blockDim.x + threadIdx.x;
    int inst = blockIdx.y;
    if (g >= kNG) return;
    int bt = inst / kV, v = inst % kV;
    int b = bt / kT;

    const float* c = centers + ((size_t)bt * kNG + g) * 3;
    float c0 = c[0], c1 = c[1], c2 = c[2];
    const float* P = fpose + (size_t)b * 16;
    float wx[4];
#pragma unroll
    for (int i = 0; i < 4; ++i)
        wx[i] = P[i * 4 + 0] * c0 + P[i * 4 + 1] * c1 + P[i * 4 + 2] * c2 + P[i * 4 + 3];

    const float* M = w2c_all + (size_t)inst * 16;
    float camx = M[0] * wx[0] + M[1] * wx[1] + M[2] * wx[2] + M[3] * wx[3];
    float camy = M[4] * wx[0] + M[5] * wx[1] + M[6] * wx[2] + M[7] * wx[3];
    float camz = M[8] * wx[0] + M[9] * wx[1] + M[10] * wx[2] + M[11] * wx[3];

    float op = clip01(opac[(size_t)bt * kNG + g]);
    bool zok = (camz > 0.001f) && isfinite(camx) && isfinite(camy) && isfinite(camz);
    if (!zok || op <= 1e-5f) return;

    const float* it = intr + ((size_t)b * kV + v) * 4;
    float fx = it[0], fy = it[1], cx = it[2], cy = it[3];
    float u = camx * fx / camz + cx;
    float vv = camy * fy / camz + cy;

    const float* sp = scale + ((size_t)bt * kNG + g) * 3;
    float sf = (sp[0] + sp[1] + sp[2]) / 3.f;
    float sg = fminf(fmaxf((fx + fy) * 0.5f * fabsf(sf) / fmaxf(camz, 0.001f), 0.75f), 10.f);

    bool inb = (u >= -3.f) && (u <= (float)kW + 2.f) && (vv >= -3.f) && (vv <= (float)kH + 2.f);
    if (!inb) return;

    atomicAdd(&sigmaSum[inst], sg);
    atomicAdd(&cnt[inst], 1);

    int x0 = (int)floorf(u);
    int y0 = (int)floorf(vv);
    if (x0 < -2 || x0 > kW + 1 || y0 < -2 || y0 > kH + 1) return;

    float bg = bgp[(size_t)bt * kNG + g];
    float dyn = clip01(1.f - bg);
    float aAll = op;
    float aDyn = clip01(op * dyn);
    float aSta = clip01(op * (1.f - dyn));
    if (aDyn <= 1e-5f) aDyn = 0.f;
    if (aSta <= 1e-5f) aSta = 0.f;

    const float* fc = feat + ((size_t)bt * kNG + g) * 3;
    float r = clip01(fc[0]), gc = clip01(fc[1]), bcl = clip01(fc[2]);

    int e = atomicAdd(entCnt, 1);
    entZ[e] = camz;
    entG[e] = g;
    int cell = inst * kNCELL + (y0 + 2) * kCX + (x0 + 2);
    entCell[e] = cell;
    atomicAdd(&cellCnt[cell], 1);

    float* p = pay + (size_t)e * 12;
    p[0] = u; p[1] = vv; p[2] = 1.f / fmaxf(sg, 0.001f);
    p[3] = aSta; p[4] = aDyn; p[5] = aAll;
    p[6] = r; p[7] = gc; p[8] = bcl; p[9] = 0.f; p[10] = 0.f; p[11] = 0.f;
}

// --- prefix sum (3 stages) → cellOff[c] = exclusive start of cell c (verbatim round-2) ---
__global__ void k_scan1(const int* __restrict__ cellCnt, int* __restrict__ cellOff,
                        int* __restrict__ blockSum) {
    __shared__ int sh[256];
    int t = threadIdx.x;
    int idx = blockIdx.x * 256 + t;
    int v = (idx < kNTOT) ? cellCnt[idx] : 0;
    sh[t] = v; __syncthreads();
    for (int o = 1; o < 256; o <<= 1) {
        int x = (t >= o) ? sh[t - o] : 0;
        __syncthreads(); sh[t] += x; __syncthreads();
    }
    if (idx < kNTOT) cellOff[idx] = sh[t] - v;
    if (t == 255) blockSum[blockIdx.x] = sh[255];
}

__global__ void k_scan2(int* __restrict__ blockSum, int* __restrict__ cellOff) {
    __shared__ int sh[256];
    int t = threadIdx.x;
    int run = 0;
    for (int chunk = 0; chunk < kNBScan; chunk += 256) {
        int i = chunk + t;
        int v = (i < kNBScan) ? blockSum[i] : 0;
        __syncthreads();
        sh[t] = v; __syncthreads();
        for (int o = 1; o < 256; o <<= 1) {
            int x = (t >= o) ? sh[t - o] : 0;
            __syncthreads(); sh[t] += x; __syncthreads();
        }
        if (i < kNBScan) blockSum[i] = run + sh[t] - v;
        run += sh[255];
    }
    if (t == 0) cellOff[kNTOT] = run;
}

__global__ void k_scan3(int* __restrict__ cellOff, const int* __restrict__ blockSum) {
    int idx = blockIdx.x * 256 + threadIdx.x;
    if (idx < kNTOT) cellOff[idx] += blockSum[idx >> 8];
}

// place entries into compact per-cell arrays (verbatim round-2; cellOff stays intact)
__global__ void k_scatter(const int* __restrict__ entCnt, const int* __restrict__ entCell,
                          const float* __restrict__ entZ, const int* __restrict__ entG,
                          const int* __restrict__ cellOff, int* __restrict__ cellCnt,
                          int2* __restrict__ szg) {
    int e = blockIdx.x * 256 + threadIdx.x;
    if (e >= entCnt[0]) return;
    int cell = entCell[e];
    int pos = cellOff[cell] + atomicSub(&cellCnt[cell], 1) - 1;
    szg[pos] = make_int2(__float_as_int(entZ[e]), (entG[e] << 16) | e);
}

// NEW: per-cell selection sort of the (z,key) pairs, ascending (z, then key)
__global__ void k_sort(const int* __restrict__ off, int2* __restrict__ szg) {
    int c = blockIdx.x * 256 + threadIdx.x;
    if (c >= kNTOT) return;
    int s = off[c], e = off[c + 1];
    if (e - s < 2) return;
    for (int i = s; i < e - 1; ++i) {
        int bj = i; int2 bv = szg[i];
        for (int j = i + 1; j < e; ++j) {
            int2 v = szg[j];
            float zv = __int_as_float(v.x), zb = __int_as_float(bv.x);
            if (zv < zb || (zv == zb && v.y < bv.y)) { bj = j; bv = v; }
        }
        if (bj != i) { szg[bj] = szg[i]; szg[i] = bv; }
    }
}

// per-pixel 25-way merge over per-CELL sorted lists (correct granularity)
__global__ __launch_bounds__(256) void k_px(const int* __restrict__ off,
                                            const int2* __restrict__ szg,
                                            const float* __restrict__ pay,
                                            float* __restrict__ out, int* __restrict__ touch) {
    int pix = blockIdx.x * blockDim.x + threadIdx.x;
    int inst = blockIdx.y;
    bool live = (pix < kHW);
    int pixc = live ? pix : (kHW - 1);
    int py = pixc / kW, px = pixc - py * kW;
    int cbase = inst * kNCELL + py * kCX + px;

    int P[25], E[25];
    unsigned long long K[25];
    int total = 0;
#pragma unroll
    for (int dy = 0; dy < 5; ++dy) {
        int c = cbase + dy * kCX;
        int o[6];
#pragma unroll
        for (int j = 0; j < 6; ++j) o[j] = off[c + j];
#pragma unroll
        for (int dx = 0; dx < 5; ++dx) {
            int li = dy * 5 + dx;
            P[li] = o[dx]; E[li] = o[dx + 1];
            total += o[dx + 1] - o[dx];
            K[li] = ~0ULL;
            if (o[dx] < o[dx + 1]) {
                int2 h = szg[o[dx]];
                K[li] = packkey(h.x, h.y);
            }
        }
    }

    float ad0 = 0.f, ad1 = 0.f, ad2 = 0.f;
    float r0 = 0.f, g0 = 0.f, b0 = 0.f;
    float r1 = 0.f, g1 = 0.f, b1 = 0.f;
    float r2 = 0.f, g2 = 0.f, b2 = 0.f;
    float fpx = (float)px, fpy = (float)py;

    for (int it = 0; it < total; ++it) {
        // tournament min over 25 head keys (keys are unique: low 16 bits = entry id)
        unsigned long long m = K[0];
#pragma unroll
        for (int li = 1; li < 25; ++li) m = (K[li] < m) ? K[li] : m;

        int e = (int)(m & 0xFFFFULL);
        const float4* pp = (const float4*)(pay + (size_t)e * 12);
        float4 q0 = pp[0];   // u, v, invss, aSta
        float4 q1 = pp[1];   // aDyn, aAll, colR, colG
        float4 q2 = pp[2];   // colB, -, -, -
        float du = (q0.x - fpx) * q0.z;
        float dv = (q0.y - fpy) * q0.z;
        float lb = expf(-0.5f * (du * du + dv * dv));

        float la, Tt, ct;
        la = fminf(lb * q0.w, 0.999f);
        Tt = clip01(1.f - ad0); ct = la * Tt;
        ad0 = fminf(ad0 + ct, 0.999f);
        r0 += q1.z * ct; g0 += q1.w * ct; b0 += q2.x * ct;

        la = fminf(lb * q1.x, 0.999f);
        Tt = clip01(1.f - ad1); ct = la * Tt;
        ad1 = fminf(ad1 + ct, 0.999f);
        r1 += q1.z * ct; g1 += q1.w * ct; b1 += q2.x * ct;

        la = fminf(lb * q1.y, 0.999f);
        Tt = clip01(1.f - ad2); ct = la * Tt;
        ad2 = fminf(ad2 + ct, 0.999f);
        r2 += q1.z * ct; g2 += q1.w * ct; b2 += q2.x * ct;

        // advance exactly the list whose head equals m (keys unique → one match)
#pragma unroll
        for (int li = 0; li < 25; ++li) {
            if (K[li] == m) {
                ++P[li];
                K[li] = ~0ULL;
                if (P[li] < E[li]) {
                    int2 h = szg[P[li]];
                    K[li] = packkey(h.x, h.y);
                }
            }
        }
    }

    unsigned long long tm = __ballot(live && ad2 > 1e-6f);
    if ((threadIdx.x & 63) == 0 && tm) atomicAdd(&touch[inst], __popcll(tm));

    if (!live) return;
    size_t o = (size_t)pix;
    size_t ib3 = (size_t)inst * 3;
    out[O_RGB_STA + (ib3 + 0) * kHW + o] = clip01(r0);
    out[O_RGB_STA + (ib3 + 1) * kHW + o] = clip01(g0);
    out[O_RGB_STA + (ib3 + 2) * kHW + o] = clip01(b0);
    out[O_RGB_DYN + (ib3 + 0) * kHW + o] = clip01(r1);
    out[O_RGB_DYN + (ib3 + 1) * kHW + o] = clip01(g1);
    out[O_RGB_DYN + (ib3 + 2) * kHW + o] = clip01(b1);
    out[O_RGB_ALL + (ib3 + 0) * kHW + o] = clip01(r2);
    out[O_RGB_ALL + (ib3 + 1) * kHW + o] = clip01(g2);
    out[O_RGB_ALL + (ib3 + 2) * kHW + o] = clip01(b2);
    out[O_A_STA + (size_t)inst * kHW + o] = ad0;
    out[O_A_DYN + (size_t)inst * kHW + o] = ad1;
    out[O_A_ALL + (size_t)inst * kHW + o] = ad2;
}

__global__ void k_fin(const float* __restrict__ sigmaSum, const int* __restrict__ cnt,
                      const int* __restrict__ touch, float* __restrict__ out) {
    if (threadIdx.x == 0 && blockIdx.x == 0) {
        float sm = 0.f, tr = 0.f;
        for (int i = 0; i < kNI; ++i) {
            sm += sigmaSum[i] / fmaxf((float)cnt[i], 1.f);
            tr += (float)touch[i] / (float)kHW;
        }
        out[O_SM] = sm / (float)kNI;
        out[O_TR] = tr / (float)kNI;
    }
}

// ---------------- launch ----------------
extern "C" void kernel_launch(void* const* d_in, const int* in_sizes, int n_in,
                              void* d_out, int out_size, void* d_ws, size_t ws_size,
                              hipStream_t stream) {
    const float* centers = (const float*)d_in[0];
    const float* scal    = (const float*)d_in[1];
    const float* feat    = (const float*)d_in[2];
    const float* opac    = (const float*)d_in[3];
    const float* bgp     = (const float*)d_in[4];
    const float* sem     = (const float*)d_in[5];
    const float* intr    = (const float*)d_in[6];
    const float* c2w     = (const float*)d_in[7];
    const float* fpose   = (const float*)d_in[8];
    float* out = (float*)d_out;
    char* ws = (char*)d_ws;

    float* w2c      = (float*)(ws + WS_W2C);
    int*   entCnt   = (int*)(ws + WS_CNTR);
    float* sigmaSum = (float*)(ws + WS_CNTR + 16);
    int*   cnt      = (int*)(ws + WS_CNTR + 48);
    int*   touch    = (int*)(ws + WS_CNTR + 80);
    int*   cellCnt  = (int*)(ws + WS_CCNT);
    int*   cellOff  = (int*)(ws + WS_COFF);
    int*   blockSum = (int*)(ws + WS_BSUM);
    int*   entCell  = (int*)(ws + WS_ECEL);
    float* entZ     = (float*)(ws + WS_EZ);
    int*   entG     = (int*)(ws + WS_EG);
    float* pay      = (float*)(ws + WS_PAY);
    int2*  szg      = (int2*)(ws + WS_SZG);

    hipMemsetAsync(ws + WS_CNTR, 0, 128, stream);
    hipMemsetAsync(ws + WS_CCNT, 0, (size_t)kNTOT * 4, stream);

    k_inv<<<1, 64, 0, stream>>>(c2w, w2c);

    dim3 gpre((kNG + 255) / 256, kNI);
    k_pre<<<gpre, 256, 0, stream>>>(centers, scal, feat, opac, bgp, intr, fpose, w2c,
                                    cellCnt, entCnt, entCell, entZ, entG, pay, sigmaSum, cnt);

    k_scan1<<<kNBScan, 256, 0, stream>>>(cellCnt, cellOff, blockSum);
    k_scan2<<<1, 256, 0, stream>>>(blockSum, cellOff);
    k_scan3<<<kNBScan, 256, 0, stream>>>(cellOff, blockSum);

    k_scatter<<<(kMaxEnt + 255) / 256, 256, 0, stream>>>(entCnt, entCell, entZ, entG,
                                                         cellOff, cellCnt, szg);

    k_sort<<<kNBScan, 256, 0, stream>>>(cellOff, szg);

    dim3 gpx((kHW + 255) / 256, kNI);
    k_px<<<gpx, 256, 0, stream>>>(cellOff, szg, pay, out, touch);

    hipMemcpyAsync(out + O_SEM, sem, (size_t)kNI * kHW * sizeof(float),
                   hipMemcpyDeviceToDevice, stream);

    k_fin<<<1, 1, 0, stream>>>(sigmaSum, cnt, touch, out);
}

// Round 5
// 171.731 us; speedup vs baseline: 1.3539x; 1.1052x over previous
//
#include <hip/hip_runtime.h>
#include <hip/hip_bf16.h>

// ---------------- problem constants ----------------
namespace {
constexpr int kB = 1, kT = 2, kV = 3;
constexpr int kGH = 32, kGW = 64;
constexpr int kNG = kV * kGH * kGW;      // 6144 gaussians per (b,t)
constexpr int kNBT = kB * kT;            // 2
constexpr int kNI = kNBT * kV;           // 6 render instances
constexpr int kH = 224, kW = 448;
constexpr int kHW = kH * kW;             // 100352
constexpr int kCX = kW + 4;              // 452 cells in x
constexpr int kCY = kH + 4;              // 228 cells in y
constexpr int kNCELL = kCX * kCY;        // 103056
constexpr int kNTOT = kNI * kNCELL;      // 618336
constexpr int kMaxEnt = kNI * kNG;       // 36864
constexpr int kNBScan = (kNTOT + 255) / 256;  // 2416

// tiling for the raster kernel: 32x8 pixels per 256-thread workgroup
constexpr int kTX = 32, kTY = 8;
constexpr int kTilesX = kW / kTX;        // 14
constexpr int kTilesY = kH / kTY;        // 28
constexpr int kNTiles = kTilesX * kTilesY; // 392
constexpr int kRowsC = kTY + 4;          // 12 cell rows per tile window
constexpr int kColsC = kTX + 4;          // 36 cells per row
constexpr int kCAP = 512;                // max candidates per tile (est. worst ~100)

// output bases (floats)
constexpr size_t RGB_SZ = (size_t)kNI * 3 * kHW;
constexpr size_t A_SZ   = (size_t)kNI * kHW;
constexpr size_t O_RGB_STA = 0;
constexpr size_t O_RGB_DYN = O_RGB_STA + RGB_SZ;
constexpr size_t O_RGB_ALL = O_RGB_DYN + RGB_SZ;
constexpr size_t O_A_STA   = O_RGB_ALL + RGB_SZ;
constexpr size_t O_A_DYN   = O_A_STA + A_SZ;
constexpr size_t O_A_ALL   = O_A_DYN + A_SZ;
constexpr size_t O_SEM     = O_A_ALL + A_SZ;
constexpr size_t O_SM      = O_SEM + A_SZ;
constexpr size_t O_TR      = O_SM + 1;

// workspace layout (bytes) — same as the round-2/4 (passed) layout
constexpr size_t WS_W2C   = 0;
constexpr size_t WS_CNTR  = 512;   // entCnt @+0, sigmaSum[6] @+16, cnt[6] @+48, touch[6] @+80
constexpr size_t WS_CCNT  = 1024;                                   // int[kNTOT]
constexpr size_t WS_COFF  = WS_CCNT + (size_t)kNTOT * 4;            // int[kNTOT+1]
constexpr size_t WS_BSUM  = WS_COFF + (size_t)(kNTOT + 1) * 4 + 12; // int[kNBScan]
constexpr size_t WS_ECEL  = WS_BSUM + (size_t)kNBScan * 4;          // int[kMaxEnt]
constexpr size_t WS_EZ    = WS_ECEL + (size_t)kMaxEnt * 4;          // f32[kMaxEnt]
constexpr size_t WS_EG    = WS_EZ + (size_t)kMaxEnt * 4;            // int[kMaxEnt]
constexpr size_t WS_PAY   = WS_EG + (size_t)kMaxEnt * 4;            // f32[12*kMaxEnt]
constexpr size_t WS_SZG   = WS_PAY + (size_t)kMaxEnt * 48;          // int2[kMaxEnt]
// end ~7.46 MB

__device__ __forceinline__ float clip01(float x) { return fminf(fmaxf(x, 0.f), 1.f); }
__device__ __forceinline__ unsigned long long packkey(int zbits, int ikey) {
    return ((unsigned long long)(unsigned)zbits << 32) | (unsigned)ikey;
}
}

// ---------------- kernels ----------------

__global__ void k_inv(const float* __restrict__ c2w, float* __restrict__ w2c) {
    int i = threadIdx.x;
    if (i >= kNI) return;
    float m[4][8];
    const float* A = c2w + (size_t)i * 16;
    for (int r = 0; r < 4; ++r)
        for (int c = 0; c < 4; ++c) { m[r][c] = A[r * 4 + c]; m[r][c + 4] = (r == c) ? 1.f : 0.f; }
    for (int col = 0; col < 4; ++col) {
        int piv = col; float mx = fabsf(m[col][col]);
        for (int r = col + 1; r < 4; ++r) { float a = fabsf(m[r][col]); if (a > mx) { mx = a; piv = r; } }
        if (piv != col)
            for (int c = 0; c < 8; ++c) { float t = m[col][c]; m[col][c] = m[piv][c]; m[piv][c] = t; }
        float inv = 1.f / m[col][col];
        for (int c = 0; c < 8; ++c) m[col][c] *= inv;
        for (int r = 0; r < 4; ++r) {
            if (r == col) continue;
            float f = m[r][col];
            for (int c = 0; c < 8; ++c) m[r][c] -= f * m[col][c];
        }
    }
    for (int r = 0; r < 4; ++r)
        for (int c = 0; c < 4; ++c) w2c[(size_t)i * 16 + r * 4 + c] = m[r][c + 4];
}

// project, stage entries, count per cell (verbatim round-4)
__global__ void k_pre(const float* __restrict__ centers, const float* __restrict__ scale,
                      const float* __restrict__ feat, const float* __restrict__ opac,
                      const float* __restrict__ bgp, const float* __restrict__ intr,
                      const float* __restrict__ fpose, const float* __restrict__ w2c_all,
                      int* __restrict__ cellCnt, int* __restrict__ entCnt,
                      int* __restrict__ entCell, float* __restrict__ entZ, int* __restrict__ entG,
                      float* __restrict__ pay, float* __restrict__ sigmaSum, int* __restrict__ cnt) {
    int g = blockIdx.x * blockDim.x + threadIdx.x;
    int inst = blockIdx.y;
    if (g >= kNG) return;
    int bt = inst / kV, v = inst % kV;
    int b = bt / kT;

    const float* c = centers + ((size_t)bt * kNG + g) * 3;
    float c0 = c[0], c1 = c[1], c2 = c[2];
    const float* P = fpose + (size_t)b * 16;
    float wx[4];
#pragma unroll
    for (int i = 0; i < 4; ++i)
        wx[i] = P[i * 4 + 0] * c0 + P[i * 4 + 1] * c1 + P[i * 4 + 2] * c2 + P[i * 4 + 3];

    const float* M = w2c_all + (size_t)inst * 16;
    float camx = M[0] * wx[0] + M[1] * wx[1] + M[2] * wx[2] + M[3] * wx[3];
    float camy = M[4] * wx[0] + M[5] * wx[1] + M[6] * wx[2] + M[7] * wx[3];
    float camz = M[8] * wx[0] + M[9] * wx[1] + M[10] * wx[2] + M[11] * wx[3];

    float op = clip01(opac[(size_t)bt * kNG + g]);
    bool zok = (camz > 0.001f) && isfinite(camx) && isfinite(camy) && isfinite(camz);
    if (!zok || op <= 1e-5f) return;

    const float* it = intr + ((size_t)b * kV + v) * 4;
    float fx = it[0], fy = it[1], cx = it[2], cy = it[3];
    float u = camx * fx / camz + cx;
    float vv = camy * fy / camz + cy;

    const float* sp = scale + ((size_t)bt * kNG + g) * 3;
    float sf = (sp[0] + sp[1] + sp[2]) / 3.f;
    float sg = fminf(fmaxf((fx + fy) * 0.5f * fabsf(sf) / fmaxf(camz, 0.001f), 0.75f), 10.f);

    bool inb = (u >= -3.f) && (u <= (float)kW + 2.f) && (vv >= -3.f) && (vv <= (float)kH + 2.f);
    if (!inb) return;

    atomicAdd(&sigmaSum[inst], sg);
    atomicAdd(&cnt[inst], 1);

    int x0 = (int)floorf(u);
    int y0 = (int)floorf(vv);
    if (x0 < -2 || x0 > kW + 1 || y0 < -2 || y0 > kH + 1) return;

    float bg = bgp[(size_t)bt * kNG + g];
    float dyn = clip01(1.f - bg);
    float aAll = op;
    float aDyn = clip01(op * dyn);
    float aSta = clip01(op * (1.f - dyn));
    if (aDyn <= 1e-5f) aDyn = 0.f;
    if (aSta <= 1e-5f) aSta = 0.f;

    const float* fc = feat + ((size_t)bt * kNG + g) * 3;
    float r = clip01(fc[0]), gc = clip01(fc[1]), bcl = clip01(fc[2]);

    int e = atomicAdd(entCnt, 1);
    entZ[e] = camz;
    entG[e] = g;
    int cell = inst * kNCELL + (y0 + 2) * kCX + (x0 + 2);
    entCell[e] = cell;
    atomicAdd(&cellCnt[cell], 1);

    float* p = pay + (size_t)e * 12;
    p[0] = u; p[1] = vv; p[2] = 1.f / fmaxf(sg, 0.001f);
    p[3] = aSta; p[4] = aDyn; p[5] = aAll;
    p[6] = r; p[7] = gc; p[8] = bcl; p[9] = 0.f; p[10] = 0.f; p[11] = 0.f;
}

// --- prefix sum (3 stages) → cellOff[c] = exclusive start of cell c (verbatim) ---
__global__ void k_scan1(const int* __restrict__ cellCnt, int* __restrict__ cellOff,
                        int* __restrict__ blockSum) {
    __shared__ int sh[256];
    int t = threadIdx.x;
    int idx = blockIdx.x * 256 + t;
    int v = (idx < kNTOT) ? cellCnt[idx] : 0;
    sh[t] = v; __syncthreads();
    for (int o = 1; o < 256; o <<= 1) {
        int x = (t >= o) ? sh[t - o] : 0;
        __syncthreads(); sh[t] += x; __syncthreads();
    }
    if (idx < kNTOT) cellOff[idx] = sh[t] - v;
    if (t == 255) blockSum[blockIdx.x] = sh[255];
}

__global__ void k_scan2(int* __restrict__ blockSum, int* __restrict__ cellOff) {
    __shared__ int sh[256];
    int t = threadIdx.x;
    int run = 0;
    for (int chunk = 0; chunk < kNBScan; chunk += 256) {
        int i = chunk + t;
        int v = (i < kNBScan) ? blockSum[i] : 0;
        __syncthreads();
        sh[t] = v; __syncthreads();
        for (int o = 1; o < 256; o <<= 1) {
            int x = (t >= o) ? sh[t - o] : 0;
            __syncthreads(); sh[t] += x; __syncthreads();
        }
        if (i < kNBScan) blockSum[i] = run + sh[t] - v;
        run += sh[255];
    }
    if (t == 0) cellOff[kNTOT] = run;
}

__global__ void k_scan3(int* __restrict__ cellOff, const int* __restrict__ blockSum) {
    int idx = blockIdx.x * 256 + threadIdx.x;
    if (idx < kNTOT) cellOff[idx] += blockSum[idx >> 8];
}

// place entries into compact per-cell arrays (verbatim; cellOff stays intact)
__global__ void k_scatter(const int* __restrict__ entCnt, const int* __restrict__ entCell,
                          const float* __restrict__ entZ, const int* __restrict__ entG,
                          const int* __restrict__ cellOff, int* __restrict__ cellCnt,
                          int2* __restrict__ szg) {
    int e = blockIdx.x * 256 + threadIdx.x;
    if (e >= entCnt[0]) return;
    int cell = entCell[e];
    int pos = cellOff[cell] + atomicSub(&cellCnt[cell], 1) - 1;
    szg[pos] = make_int2(__float_as_int(entZ[e]), (entG[e] << 16) | e);
}

// tiled rasterizer: 32x8 pixels per 256-thread WG; gather tile candidates to LDS,
// rank-sort by (z,g), then all pixels sweep the sorted list in lockstep.
__global__ __launch_bounds__(256) void k_tile(const int* __restrict__ off,
                                              const int2* __restrict__ szg,
                                              const float* __restrict__ pay,
                                              float* __restrict__ out,
                                              int* __restrict__ touch) {
    __shared__ int shRowS[kRowsC];
    __shared__ int shRowD[kRowsC + 1];
    __shared__ unsigned long long shKey[kCAP];
    __shared__ float4 shRec[kCAP * 3];

    int t = threadIdx.x;
    int tile = blockIdx.x;
    int inst = blockIdx.y;
    int tx = (tile % kTilesX) * kTX;
    int ty = (tile / kTilesX) * kTY;
    int instBase = inst * kNCELL;

    // row ranges: cell rows ty..ty+11, cols tx..tx+35
    if (t < kRowsC) {
        int c = instBase + (ty + t) * kCX + tx;
        shRowS[t] = off[c];
        shRowD[t + 1] = off[c + kColsC] - off[c];
    }
    __syncthreads();
    if (t == 0) {
        shRowD[0] = 0;
        for (int r = 0; r < kRowsC; ++r) shRowD[r + 1] += shRowD[r];
    }
    __syncthreads();
    int N = shRowD[kRowsC];
    if (N > kCAP) N = kCAP;   // est. worst tile ~100 << 512; safety clamp

    // gather: thread t handles entries t and t+256 (kCAP=512)
    float4 a0, a1, a2, b0, b1, b2;
    unsigned long long keyA = ~0ULL, keyB = ~0ULL;
    int iA = t, iB = t + 256;
    if (iA < N) {
        int r = 0;
        while (iA >= shRowD[r + 1]) ++r;
        int src = shRowS[r] + (iA - shRowD[r]);
        int2 zk = szg[src];
        keyA = packkey(zk.x, zk.y);
        shKey[iA] = keyA;
        const float4* pp = (const float4*)(pay + (size_t)(zk.y & 0xFFFF) * 12);
        a0 = pp[0]; a1 = pp[1]; a2 = pp[2];
    }
    if (iB < N) {
        int r = 0;
        while (iB >= shRowD[r + 1]) ++r;
        int src = shRowS[r] + (iB - shRowD[r]);
        int2 zk = szg[src];
        keyB = packkey(zk.x, zk.y);
        shKey[iB] = keyB;
        const float4* pp = (const float4*)(pay + (size_t)(zk.y & 0xFFFF) * 12);
        b0 = pp[0]; b1 = pp[1]; b2 = pp[2];
    }
    __syncthreads();

    // rank sort (keys unique: low 16 bits = entry id)
    int rkA = 0, rkB = 0;
    for (int j = 0; j < N; ++j) {
        unsigned long long kj = shKey[j];
        rkA += (kj < keyA);
        rkB += (kj < keyB);
    }
    __syncthreads();   // done reading shKey region before writing shRec? (separate arrays; barrier for ordering only)
    if (iA < N) { shRec[rkA * 3 + 0] = a0; shRec[rkA * 3 + 1] = a1; shRec[rkA * 3 + 2] = a2; }
    if (iB < N) { shRec[rkB * 3 + 0] = b0; shRec[rkB * 3 + 1] = b1; shRec[rkB * 3 + 2] = b2; }
    __syncthreads();

    // composite: pixel per thread, lockstep sweep of sorted list
    int px = tx + (t & (kTX - 1));
    int py = ty + (t >> 5);
    float fpx = (float)px, fpy = (float)py;

    float ad0 = 0.f, ad1 = 0.f, ad2 = 0.f;
    float r0 = 0.f, g0 = 0.f, bb0 = 0.f;
    float r1 = 0.f, g1 = 0.f, bb1 = 0.f;
    float r2 = 0.f, g2 = 0.f, bb2 = 0.f;

    for (int k = 0; k < N; ++k) {
        float4 q0 = shRec[k * 3 + 0];   // u, v, invss, aSta
        float4 q1 = shRec[k * 3 + 1];   // aDyn, aAll, colR, colG
        float4 q2 = shRec[k * 3 + 2];   // colB, -, -, -
        float x0 = floorf(q0.x);
        float y0 = floorf(q0.y);
        float dxc = fpx - x0, dyc = fpy - y0;
        bool keep = (dxc >= -2.f) & (dxc <= 2.f) & (dyc >= -2.f) & (dyc <= 2.f);
        float du = (q0.x - fpx) * q0.z;
        float dv = (q0.y - fpy) * q0.z;
        float lb = expf(-0.5f * (du * du + dv * dv));
        lb = keep ? lb : 0.f;

        float la, Tt, ct;
        la = fminf(lb * q0.w, 0.999f);
        Tt = clip01(1.f - ad0); ct = la * Tt;
        ad0 = fminf(ad0 + ct, 0.999f);
        r0 += q1.z * ct; g0 += q1.w * ct; bb0 += q2.x * ct;

        la = fminf(lb * q1.x, 0.999f);
        Tt = clip01(1.f - ad1); ct = la * Tt;
        ad1 = fminf(ad1 + ct, 0.999f);
        r1 += q1.z * ct; g1 += q1.w * ct; bb1 += q2.x * ct;

        la = fminf(lb * q1.y, 0.999f);
        Tt = clip01(1.f - ad2); ct = la * Tt;
        ad2 = fminf(ad2 + ct, 0.999f);
        r2 += q1.z * ct; g2 += q1.w * ct; bb2 += q2.x * ct;
    }

    unsigned long long tm = __ballot(ad2 > 1e-6f);
    if ((t & 63) == 0 && tm) atomicAdd(&touch[inst], __popcll(tm));

    size_t o = (size_t)py * kW + px;
    size_t ib3 = (size_t)inst * 3;
    out[O_RGB_STA + (ib3 + 0) * kHW + o] = clip01(r0);
    out[O_RGB_STA + (ib3 + 1) * kHW + o] = clip01(g0);
    out[O_RGB_STA + (ib3 + 2) * kHW + o] = clip01(bb0);
    out[O_RGB_DYN + (ib3 + 0) * kHW + o] = clip01(r1);
    out[O_RGB_DYN + (ib3 + 1) * kHW + o] = clip01(g1);
    out[O_RGB_DYN + (ib3 + 2) * kHW + o] = clip01(bb1);
    out[O_RGB_ALL + (ib3 + 0) * kHW + o] = clip01(r2);
    out[O_RGB_ALL + (ib3 + 1) * kHW + o] = clip01(g2);
    out[O_RGB_ALL + (ib3 + 2) * kHW + o] = clip01(bb2);
    out[O_A_STA + (size_t)inst * kHW + o] = ad0;
    out[O_A_DYN + (size_t)inst * kHW + o] = ad1;
    out[O_A_ALL + (size_t)inst * kHW + o] = ad2;
}

__global__ void k_fin(const float* __restrict__ sigmaSum, const int* __restrict__ cnt,
                      const int* __restrict__ touch, float* __restrict__ out) {
    if (threadIdx.x == 0 && blockIdx.x == 0) {
        float sm = 0.f, tr = 0.f;
        for (int i = 0; i < kNI; ++i) {
            sm += sigmaSum[i] / fmaxf((float)cnt[i], 1.f);
            tr += (float)touch[i] / (float)kHW;
        }
        out[O_SM] = sm / (float)kNI;
        out[O_TR] = tr / (float)kNI;
    }
}

// ---------------- launch ----------------
extern "C" void kernel_launch(void* const* d_in, const int* in_sizes, int n_in,
                              void* d_out, int out_size, void* d_ws, size_t ws_size,
                              hipStream_t stream) {
    const float* centers = (const float*)d_in[0];
    const float* scal    = (const float*)d_in[1];
    const float* feat    = (const float*)d_in[2];
    const float* opac    = (const float*)d_in[3];
    const float* bgp     = (const float*)d_in[4];
    const float* sem     = (const float*)d_in[5];
    const float* intr    = (const float*)d_in[6];
    const float* c2w     = (const float*)d_in[7];
    const float* fpose   = (const float*)d_in[8];
    float* out = (float*)d_out;
    char* ws = (char*)d_ws;

    float* w2c      = (float*)(ws + WS_W2C);
    int*   entCnt   = (int*)(ws + WS_CNTR);
    float* sigmaSum = (float*)(ws + WS_CNTR + 16);
    int*   cnt      = (int*)(ws + WS_CNTR + 48);
    int*   touch    = (int*)(ws + WS_CNTR + 80);
    int*   cellCnt  = (int*)(ws + WS_CCNT);
    int*   cellOff  = (int*)(ws + WS_COFF);
    int*   blockSum = (int*)(ws + WS_BSUM);
    int*   entCell  = (int*)(ws + WS_ECEL);
    float* entZ     = (float*)(ws + WS_EZ);
    int*   entG     = (int*)(ws + WS_EG);
    float* pay      = (float*)(ws + WS_PAY);
    int2*  szg      = (int2*)(ws + WS_SZG);

    hipMemsetAsync(ws + WS_CNTR, 0, 128, stream);
    hipMemsetAsync(ws + WS_CCNT, 0, (size_t)kNTOT * 4, stream);

    k_inv<<<1, 64, 0, stream>>>(c2w, w2c);

    dim3 gpre((kNG + 255) / 256, kNI);
    k_pre<<<gpre, 256, 0, stream>>>(centers, scal, feat, opac, bgp, intr, fpose, w2c,
                                    cellCnt, entCnt, entCell, entZ, entG, pay, sigmaSum, cnt);

    k_scan1<<<kNBScan, 256, 0, stream>>>(cellCnt, cellOff, blockSum);
    k_scan2<<<1, 256, 0, stream>>>(blockSum, cellOff);
    k_scan3<<<kNBScan, 256, 0, stream>>>(cellOff, blockSum);

    k_scatter<<<(kMaxEnt + 255) / 256, 256, 0, stream>>>(entCnt, entCell, entZ, entG,
                                                         cellOff, cellCnt, szg);

    dim3 gtile(kNTiles, kNI);
    k_tile<<<gtile, 256, 0, stream>>>(cellOff, szg, pay, out, touch);

    hipMemcpyAsync(out + O_SEM, sem, (size_t)kNI * kHW * sizeof(float),
                   hipMemcpyDeviceToDevice, stream);

    k_fin<<<1, 1, 0, stream>>>(sigmaSum, cnt, touch, out);
}

// Round 6
// 150.044 us; speedup vs baseline: 1.5496x; 1.1445x over previous
//
#include <hip/hip_runtime.h>
#include <hip/hip_bf16.h>
#include <hip/hip_fp16.h>

// ---------------- problem constants ----------------
namespace {
constexpr int kB = 1, kT = 2, kV = 3;
constexpr int kGH = 32, kGW = 64;
constexpr int kNG = kV * kGH * kGW;      // 6144 gaussians per (b,t)
constexpr int kNBT = kB * kT;            // 2
constexpr int kNI = kNBT * kV;           // 6 render instances
constexpr int kH = 224, kW = 448;
constexpr int kHW = kH * kW;             // 100352

// tile rasterizer: 32x8 pixels per 256-thread WG, 5x5 gaussian footprint
constexpr int kTX = 32, kTY = 8;
constexpr int kTilesX = kW / kTX;        // 14
constexpr int kTilesY = kH / kTY;        // 28
constexpr int kNTiles = kTilesX * kTilesY; // 392
constexpr int kNBins = kNI * kNTiles;    // 2352
constexpr int kCAP = 512;                // per-tile candidate capacity (max N proven <=512 in r5)
constexpr int kMaxEnt = kNI * kNG;       // 36864

// output bases (floats)
constexpr size_t RGB_SZ = (size_t)kNI * 3 * kHW;
constexpr size_t A_SZ   = (size_t)kNI * kHW;
constexpr size_t O_RGB_STA = 0;
constexpr size_t O_RGB_DYN = O_RGB_STA + RGB_SZ;
constexpr size_t O_RGB_ALL = O_RGB_DYN + RGB_SZ;
constexpr size_t O_A_STA   = O_RGB_ALL + RGB_SZ;
constexpr size_t O_A_DYN   = O_A_STA + A_SZ;
constexpr size_t O_A_ALL   = O_A_DYN + A_SZ;
constexpr size_t O_SEM     = O_A_ALL + A_SZ;
constexpr size_t O_SM      = O_SEM + A_SZ;
constexpr size_t O_TR      = O_SM + 1;

// workspace layout (bytes), total ~6.6 MB (< 7.46 MB proven available)
constexpr size_t WS_W2C   = 0;     // 6*16 f32
constexpr size_t WS_CNTR  = 512;   // entCnt @+0, sigmaSum[6] @+16, cnt[6] @+48, touch[6] @+80
constexpr size_t WS_TCNT  = 1024;                                   // int[kNBins] = 9408 B
constexpr size_t WS_TLIST = 10432;                                  // int[kNBins*kCAP] = 4,816,896 B
constexpr size_t WS_PAY   = WS_TLIST + (size_t)kNBins * kCAP * 4;   // f32[12*kMaxEnt] = 1,769,472 B

// payload per entry (12 floats):
//  p0 = (u, v, invss, aSta) ; p1 = (aDyn, aAll, colR, colG) ; p2 = (colB, zbits, keybits, 0)
//  keybits = (g<<16)|e  as int

__device__ __forceinline__ float clip01(float x) { return fminf(fmaxf(x, 0.f), 1.f); }
__device__ __forceinline__ unsigned long long packkey(int zbits, int ikey) {
    return ((unsigned long long)(unsigned)zbits << 32) | (unsigned)ikey;
}
__device__ __forceinline__ float packh2(float a, float b) {
    __half2 h = __floats2half2_rn(a, b);
    return __uint_as_float(*reinterpret_cast<unsigned*>(&h));
}
__device__ __forceinline__ float2 unpackh2(float f) {
    unsigned u = __float_as_uint(f);
    return __half22float2(*reinterpret_cast<__half2*>(&u));
}
}

// ---------------- kernels ----------------

__global__ void k_inv(const float* __restrict__ c2w, float* __restrict__ w2c) {
    int i = threadIdx.x;
    if (i >= kNI) return;
    float m[4][8];
    const float* A = c2w + (size_t)i * 16;
    for (int r = 0; r < 4; ++r)
        for (int c = 0; c < 4; ++c) { m[r][c] = A[r * 4 + c]; m[r][c + 4] = (r == c) ? 1.f : 0.f; }
    for (int col = 0; col < 4; ++col) {
        int piv = col; float mx = fabsf(m[col][col]);
        for (int r = col + 1; r < 4; ++r) { float a = fabsf(m[r][col]); if (a > mx) { mx = a; piv = r; } }
        if (piv != col)
            for (int c = 0; c < 8; ++c) { float t = m[col][c]; m[col][c] = m[piv][c]; m[piv][c] = t; }
        float inv = 1.f / m[col][col];
        for (int c = 0; c < 8; ++c) m[col][c] *= inv;
        for (int r = 0; r < 4; ++r) {
            if (r == col) continue;
            float f = m[r][col];
            for (int c = 0; c < 8; ++c) m[r][c] -= f * m[col][c];
        }
    }
    for (int r = 0; r < 4; ++r)
        for (int c = 0; c < 4; ++c) w2c[(size_t)i * 16 + r * 4 + c] = m[r][c + 4];
}

// project, emit payloads, append entry ids into per-tile bins, wave-reduced stats
__global__ void k_pre(const float* __restrict__ centers, const float* __restrict__ scale,
                      const float* __restrict__ feat, const float* __restrict__ opac,
                      const float* __restrict__ bgp, const float* __restrict__ intr,
                      const float* __restrict__ fpose, const float* __restrict__ w2c_all,
                      int* __restrict__ entCnt, float* __restrict__ sigmaSum, int* __restrict__ cnt,
                      int* __restrict__ tileCnt, int* __restrict__ tileList,
                      float* __restrict__ pay) {
    int g = blockIdx.x * 256 + threadIdx.x;   // grid sized exactly: no early exit (wave shfl below)
    int inst = blockIdx.y;
    int bt = inst / kV, v = inst % kV;
    int b = bt / kT;

    const float* c = centers + ((size_t)bt * kNG + g) * 3;
    float c0 = c[0], c1 = c[1], c2 = c[2];
    const float* P = fpose + (size_t)b * 16;
    float wx[4];
#pragma unroll
    for (int i = 0; i < 4; ++i)
        wx[i] = P[i * 4 + 0] * c0 + P[i * 4 + 1] * c1 + P[i * 4 + 2] * c2 + P[i * 4 + 3];

    const float* M = w2c_all + (size_t)inst * 16;
    float camx = M[0] * wx[0] + M[1] * wx[1] + M[2] * wx[2] + M[3] * wx[3];
    float camy = M[4] * wx[0] + M[5] * wx[1] + M[6] * wx[2] + M[7] * wx[3];
    float camz = M[8] * wx[0] + M[9] * wx[1] + M[10] * wx[2] + M[11] * wx[3];

    float op = clip01(opac[(size_t)bt * kNG + g]);
    bool zok = (camz > 0.001f) && isfinite(camx) && isfinite(camy) && isfinite(camz);
    bool valid0 = zok && (op > 1e-5f);

    const float* it = intr + ((size_t)b * kV + v) * 4;
    float fx = it[0], fy = it[1], cx = it[2], cy = it[3];
    float u = camx * fx / camz + cx;
    float vv = camy * fy / camz + cy;

    const float* sp = scale + ((size_t)bt * kNG + g) * 3;
    float sf = (sp[0] + sp[1] + sp[2]) / 3.f;
    float sg = fminf(fmaxf((fx + fy) * 0.5f * fabsf(sf) / fmaxf(camz, 0.001f), 0.75f), 10.f);

    bool inb = (u >= -3.f) && (u <= (float)kW + 2.f) && (vv >= -3.f) && (vv <= (float)kH + 2.f);
    bool statsValid = valid0 && inb;

    // wave-reduced sigma/cnt stats (1 atomic pair per wave)
    float ssum = statsValid ? sg : 0.f;
    int scnt = statsValid ? 1 : 0;
#pragma unroll
    for (int o = 32; o > 0; o >>= 1) {
        ssum += __shfl_down(ssum, o);
        scnt += __shfl_down(scnt, o);
    }
    if ((threadIdx.x & 63) == 0 && scnt > 0) {
        atomicAdd(&sigmaSum[inst], ssum);
        atomicAdd(&cnt[inst], scnt);
    }

    int x0 = (int)floorf(u);
    int y0 = (int)floorf(vv);
    bool emit = statsValid && (x0 >= -2) && (x0 <= kW + 1) && (y0 >= -2) && (y0 <= kH + 1);
    if (!emit) return;

    float bg = bgp[(size_t)bt * kNG + g];
    float dyn = clip01(1.f - bg);
    float aAll = op;
    float aDyn = clip01(op * dyn);
    float aSta = clip01(op * (1.f - dyn));
    if (aDyn <= 1e-5f) aDyn = 0.f;
    if (aSta <= 1e-5f) aSta = 0.f;

    const float* fc = feat + ((size_t)bt * kNG + g) * 3;
    float r = clip01(fc[0]), gc = clip01(fc[1]), bcl = clip01(fc[2]);

    int e = atomicAdd(entCnt, 1);
    float4* p4 = (float4*)(pay + (size_t)e * 12);
    int keybits = (g << 16) | e;
    p4[0] = make_float4(u, vv, 1.f / fmaxf(sg, 0.001f), aSta);
    p4[1] = make_float4(aDyn, aAll, r, gc);
    p4[2] = make_float4(bcl, camz, __int_as_float(keybits), 0.f);

    // append to all overlapping 32x8 tiles: cell (cx2,cy2) in tile (i,j) iff
    // 32i <= cx2 <= 32i+35  and  8j <= cy2 <= 8j+11
    int cx2 = x0 + 2, cy2 = y0 + 2;
    int ilo = (cx2 - 4) / 32; if (ilo < 0) ilo = 0;       // = max(0, ceil((cx2-35)/32))
    int ihi = min(kTilesX - 1, cx2 / 32);
    int jlo = (cy2 - 4) / 8;  if (jlo < 0) jlo = 0;       // = max(0, ceil((cy2-11)/8))
    int jhi = min(kTilesY - 1, cy2 / 8);
    for (int j = jlo; j <= jhi; ++j)
        for (int i = ilo; i <= ihi; ++i) {
            int bin = inst * kNTiles + j * kTilesX + i;
            int idx = atomicAdd(&tileCnt[bin], 1);
            if (idx < kCAP) tileList[(size_t)bin * kCAP + idx] = e;
        }
}

// tiled rasterizer: gather own bin, rank-sort by (z,g), lockstep composite with ballot-skip
__global__ __launch_bounds__(256) void k_tile(const int* __restrict__ tileCnt,
                                              const int* __restrict__ tileList,
                                              const float* __restrict__ pay,
                                              float* __restrict__ out,
                                              int* __restrict__ touch) {
    __shared__ unsigned long long shKey[kCAP];
    __shared__ float4 shRec[kCAP * 2];

    int t = threadIdx.x;
    int tile = blockIdx.x;
    int inst = blockIdx.y;
    int bin = inst * kNTiles + tile;
    int N = tileCnt[bin];
    if (N > kCAP) N = kCAP;

    // gather: thread t handles entries t and t+256
    unsigned long long keyA = ~0ULL, keyB = ~0ULL;
    float4 raA, rbA, raB, rbB;
    int iA = t, iB = t + 256;
    if (iA < N) {
        int e = tileList[(size_t)bin * kCAP + iA];
        const float4* pp = (const float4*)(pay + (size_t)e * 12);
        float4 p0 = pp[0], p1 = pp[1], p2 = pp[2];
        keyA = packkey(__float_as_int(p2.y), __float_as_int(p2.z));
        shKey[iA] = keyA;
        raA = p0;
        rbA = make_float4(p1.x, p1.y, packh2(p1.z, p1.w), packh2(p2.x, 0.f));
    }
    if (iB < N) {
        int e = tileList[(size_t)bin * kCAP + iB];
        const float4* pp = (const float4*)(pay + (size_t)e * 12);
        float4 p0 = pp[0], p1 = pp[1], p2 = pp[2];
        keyB = packkey(__float_as_int(p2.y), __float_as_int(p2.z));
        shKey[iB] = keyB;
        raB = p0;
        rbB = make_float4(p1.x, p1.y, packh2(p1.z, p1.w), packh2(p2.x, 0.f));
    }
    __syncthreads();

    // rank sort (keys unique: low bits contain entry id)
    int rkA = 0, rkB = 0;
    for (int j = 0; j < N; ++j) {
        unsigned long long kj = shKey[j];
        rkA += (kj < keyA);
        rkB += (kj < keyB);
    }
    if (iA < N) { shRec[rkA * 2 + 0] = raA; shRec[rkA * 2 + 1] = rbA; }
    if (iB < N) { shRec[rkB * 2 + 0] = raB; shRec[rkB * 2 + 1] = rbB; }
    __syncthreads();

    // composite: pixel per thread; wave covers 2 pixel rows -> ballot-skip
    int tx = (tile % kTilesX) * kTX;
    int ty = (tile / kTilesX) * kTY;
    int px = tx + (t & (kTX - 1));
    int py = ty + (t >> 5);
    float fpx = (float)px, fpy = (float)py;

    float ad0 = 0.f, ad1 = 0.f, ad2 = 0.f;
    float r0 = 0.f, g0 = 0.f, b0 = 0.f;
    float r1 = 0.f, g1 = 0.f, b1 = 0.f;
    float r2 = 0.f, g2 = 0.f, b2 = 0.f;

    for (int k = 0; k < N; ++k) {
        float4 q0 = shRec[k * 2 + 0];   // u, v, invss, aSta
        float dxc = fpx - floorf(q0.x);
        float dyc = fpy - floorf(q0.y);
        bool keep = (dxc >= -2.f) && (dxc <= 2.f) && (dyc >= -2.f) && (dyc <= 2.f);
        if (__ballot(keep) == 0ULL) continue;
        float4 q1 = shRec[k * 2 + 1];   // aDyn, aAll, h2(r,g), h2(b,0)
        float du = (q0.x - fpx) * q0.z;
        float dv = (q0.y - fpy) * q0.z;
        float lb = expf(-0.5f * (du * du + dv * dv));
        lb = keep ? lb : 0.f;
        float2 crg = unpackh2(q1.z);
        float cb = unpackh2(q1.w).x;

        float la, Tt, ct;
        la = fminf(lb * q0.w, 0.999f);
        Tt = clip01(1.f - ad0); ct = la * Tt;
        ad0 = fminf(ad0 + ct, 0.999f);
        r0 += crg.x * ct; g0 += crg.y * ct; b0 += cb * ct;

        la = fminf(lb * q1.x, 0.999f);
        Tt = clip01(1.f - ad1); ct = la * Tt;
        ad1 = fminf(ad1 + ct, 0.999f);
        r1 += crg.x * ct; g1 += crg.y * ct; b1 += cb * ct;

        la = fminf(lb * q1.y, 0.999f);
        Tt = clip01(1.f - ad2); ct = la * Tt;
        ad2 = fminf(ad2 + ct, 0.999f);
        r2 += crg.x * ct; g2 += crg.y * ct; b2 += cb * ct;
    }

    unsigned long long tm = __ballot(ad2 > 1e-6f);
    if ((t & 63) == 0 && tm) atomicAdd(&touch[inst], __popcll(tm));

    size_t o = (size_t)py * kW + px;
    size_t ib3 = (size_t)inst * 3;
    out[O_RGB_STA + (ib3 + 0) * kHW + o] = clip01(r0);
    out[O_RGB_STA + (ib3 + 1) * kHW + o] = clip01(g0);
    out[O_RGB_STA + (ib3 + 2) * kHW + o] = clip01(b0);
    out[O_RGB_DYN + (ib3 + 0) * kHW + o] = clip01(r1);
    out[O_RGB_DYN + (ib3 + 1) * kHW + o] = clip01(g1);
    out[O_RGB_DYN + (ib3 + 2) * kHW + o] = clip01(b1);
    out[O_RGB_ALL + (ib3 + 0) * kHW + o] = clip01(r2);
    out[O_RGB_ALL + (ib3 + 1) * kHW + o] = clip01(g2);
    out[O_RGB_ALL + (ib3 + 2) * kHW + o] = clip01(b2);
    out[O_A_STA + (size_t)inst * kHW + o] = ad0;
    out[O_A_DYN + (size_t)inst * kHW + o] = ad1;
    out[O_A_ALL + (size_t)inst * kHW + o] = ad2;
}

__global__ void k_fin(const float* __restrict__ sigmaSum, const int* __restrict__ cnt,
                      const int* __restrict__ touch, float* __restrict__ out) {
    if (threadIdx.x == 0 && blockIdx.x == 0) {
        float sm = 0.f, tr = 0.f;
        for (int i = 0; i < kNI; ++i) {
            sm += sigmaSum[i] / fmaxf((float)cnt[i], 1.f);
            tr += (float)touch[i] / (float)kHW;
        }
        out[O_SM] = sm / (float)kNI;
        out[O_TR] = tr / (float)kNI;
    }
}

// ---------------- launch ----------------
extern "C" void kernel_launch(void* const* d_in, const int* in_sizes, int n_in,
                              void* d_out, int out_size, void* d_ws, size_t ws_size,
                              hipStream_t stream) {
    const float* centers = (const float*)d_in[0];
    const float* scal    = (const float*)d_in[1];
    const float* feat    = (const float*)d_in[2];
    const float* opac    = (const float*)d_in[3];
    const float* bgp     = (const float*)d_in[4];
    const float* sem     = (const float*)d_in[5];
    const float* intr    = (const float*)d_in[6];
    const float* c2w     = (const float*)d_in[7];
    const float* fpose   = (const float*)d_in[8];
    float* out = (float*)d_out;
    char* ws = (char*)d_ws;

    float* w2c      = (float*)(ws + WS_W2C);
    int*   entCnt   = (int*)(ws + WS_CNTR);
    float* sigmaSum = (float*)(ws + WS_CNTR + 16);
    int*   cnt      = (int*)(ws + WS_CNTR + 48);
    int*   touch    = (int*)(ws + WS_CNTR + 80);
    int*   tileCnt  = (int*)(ws + WS_TCNT);
    int*   tileList = (int*)(ws + WS_TLIST);
    float* pay      = (float*)(ws + WS_PAY);

    // zero counters + tile counts in one small memset (512 .. 10432)
    hipMemsetAsync(ws + WS_CNTR, 0, WS_TLIST - WS_CNTR, stream);

    k_inv<<<1, 64, 0, stream>>>(c2w, w2c);

    dim3 gpre(kNG / 256, kNI);   // 6144 = 24*256 exactly (no partial wave: shfl-reduce safe)
    k_pre<<<gpre, 256, 0, stream>>>(centers, scal, feat, opac, bgp, intr, fpose, w2c,
                                    entCnt, sigmaSum, cnt, tileCnt, tileList, pay);

    dim3 gtile(kNTiles, kNI);
    k_tile<<<gtile, 256, 0, stream>>>(tileCnt, tileList, pay, out, touch);

    hipMemcpyAsync(out + O_SEM, sem, (size_t)kNI * kHW * sizeof(float),
                   hipMemcpyDeviceToDevice, stream);

    k_fin<<<1, 1, 0, stream>>>(sigmaSum, cnt, touch, out);
}